// Round 15
// baseline (1543.467 us; speedup 1.0000x reference)
//
#include <hip/hip_runtime.h>

typedef unsigned short u16;
typedef _Float16 f16;
typedef __attribute__((ext_vector_type(4))) float f32x4;
typedef __attribute__((ext_vector_type(16))) float f32x16;
typedef __attribute__((ext_vector_type(8))) _Float16 f16x8;
typedef __attribute__((ext_vector_type(8))) unsigned short u16x8;

#define NIMG 8
#define HH 100
#define WW 152
#define HP 102
#define WP 154
#define NPIX (NIMG*HH*WW)                       // 121600
#define ACT_ELEMS ((size_t)NIMG*HP*WP*256)      // 32,169,984
#define ACT_BYTES (ACT_ELEMS*2)

__device__ __forceinline__ u16 f2h(float x){
    f16 h = (f16)x;                       // v_cvt_f16_f32, RNE
    return __builtin_bit_cast(u16, h);
}

__device__ __forceinline__ void g2l16(const u16* g, u16* l){
    __builtin_amdgcn_global_load_lds((const __attribute__((address_space(1))) unsigned int*)g,
                                     (__attribute__((address_space(3))) unsigned int*)l, 16, 0, 0);
}

// ---------------- border zeroing (pads of all four ping-pong activation buffers) ----------------
__global__ void zero_borders(u16* A, u16* B, u16* C, u16* D){
    int id = blockIdx.x*256 + threadIdx.x;            // 8*508*32 = 130048 exact
    int ch = id & 31; int t = id >> 5;
    int pb = t % 508; int nimg = t / 508;
    int hp, wp;
    if (pb < 154)      { hp = 0;            wp = pb; }
    else if (pb < 308) { hp = 101;          wp = pb - 154; }
    else if (pb < 408) { hp = pb - 308 + 1; wp = 0; }
    else               { hp = pb - 408 + 1; wp = 153; }
    size_t off = ((size_t)((nimg*HP + hp)*WP + wp))*256 + ch*8;
    u16x8 z = {};
    *(u16x8*)(A+off) = z; *(u16x8*)(B+off) = z;
    *(u16x8*)(C+off) = z; *(u16x8*)(D+off) = z;
}

// ---------------- NCHW fp32 feature -> padded NHWC fp16 (both tower inputs) ----------------
__global__ void feat2act(const float* __restrict__ F, u16* __restrict__ D1, u16* __restrict__ D2){
    __shared__ float t[64][65];
    int bid = blockIdx.x;
    int wb = bid % 3; bid /= 3;
    int cb = bid & 3; bid >>= 2;
    int h = bid % 100; int nimg = bid / 100;
    int c0 = cb*64, w0 = wb*64;
    int tid = threadIdx.x;
    int cl = tid >> 6;
    int wl = tid & 63;
    #pragma unroll
    for (int rr=0; rr<16; ++rr){
        int c = rr*4 + cl;
        int w = w0 + wl;
        float v = 0.f;
        if (w < WW) v = F[ ((size_t)((nimg*256 + c0 + c)*HH + h))*WW + w ];
        t[c][wl] = v;
    }
    __syncthreads();
    int wl2 = tid >> 6;
    int cl2 = tid & 63;
    #pragma unroll
    for (int rr=0; rr<16; ++rr){
        int w = rr*4 + wl2;
        if (w0 + w < WW){
            u16 h16 = f2h(t[cl2][w]);
            size_t dst = ((size_t)((nimg*HP + h + 1)*WP + (w0 + w + 1)))*256 + c0 + cl2;
            D1[dst] = h16;
            D2[dst] = h16;
        }
    }
}

// ---------------- weight transforms: OIHW fp32 -> [tap][co][ci] fp16 ----------------
__global__ void wt_tower(const float* __restrict__ srcC, const float* __restrict__ srcB,
                         u16* __restrict__ dC, u16* __restrict__ dB){
    int gidx = blockIdx.x*256 + threadIdx.x;       // 2 * 4*9*256*256
    const int HALF = 4*9*256*256;
    const float* src = (gidx < HALF) ? srcC : srcB;
    u16* d           = (gidx < HALF) ? dC : dB;
    int idx = (gidx < HALF) ? gidx : gidx - HALF;
    int ci = idx & 255; int t = idx >> 8;
    int co = t & 255; t >>= 8;
    int tap = t % 9; int l = t / 9;
    d[idx] = f2h(src[ ((size_t)((l*256+co)*256+ci))*9 + tap ]);
}
__global__ void wt_predctn(const float* __restrict__ pw, const float* __restrict__ cw,
                           u16* __restrict__ d){
    int idx = blockIdx.x*256 + threadIdx.x;        // 9*128*256 exact (1152 blocks)
    int ci = idx & 255; int co = (idx>>8) & 127; int tap = idx >> 15;
    float v = 0.f;
    if (co < 64)       v = pw[ ((size_t)(co*256+ci))*9 + tap ];
    else if (co == 64) v = cw[ (size_t)ci*9 + tap ];
    d[idx] = f2h(v);
}
__global__ void wt_score(const float* __restrict__ sw, u16* __restrict__ d){
    int idx = blockIdx.x*256 + threadIdx.x;        // 9*128*256 exact (1152 blocks)
    int ci = idx & 255; int co = (idx>>8) & 127; int tap = idx >> 15;
    d[idx] = f2h((co == 0) ? sw[ (size_t)ci*9 + tap ] : 0.f);
}
__global__ void prep_bias(const float* pb, const float* cb, const float* sb, float* bpc, float* bsc){
    int i = threadIdx.x;      // 128
    bpc[i] = (i < 64) ? pb[i] : ((i == 64) ? cb[0] : 0.f);
    bsc[i] = (i == 0) ? sb[0] : 0.f;
}

// ============ tower conv: 128px x 256co tile, BK=64, MFMA 32x32x16 (2x2 tiles/wave) ============
// Identical staging/protocol/LDS to the proven r14 kernel; only the MFMA shape changes:
// 16 x mfma_f32_32x32x16_f16 per step (vs 32 x 16x16x32) — same LDS bytes, -17% matrix-pipe
// cycles (m119: 8.07cy/32KFLOP vs 9.7) and half the issue slots.
// acc: f32x16 acc[2][2] = 64 VGPR (same).  C/D layout (m74/m101, dtype-independent):
//   col = lane&31, row = (reg&3) + 8*(reg>>2) + 4*(lane>>5).
// A/B frag (32x32x16): row/col = lane&31, k = (lane>>5)*8 + j  -> one b128 per frag.
__global__ __launch_bounds__(256, 2) void conv_tower32(
    const u16* __restrict__ Ain0, const u16* __restrict__ Ain1,
    const u16* __restrict__ W0,  const u16* __restrict__ W1,
    const float* __restrict__ bias0, const float* __restrict__ bias1,
    u16* __restrict__ Oh0, u16* __restrict__ Oh1)
{
    __shared__ u16 lds[32768];   // 64 KiB (2 buffers; buf stride 16384: A@0, B@8192)
    const int tid  = threadIdx.x;
    const int lane = tid & 63;
    const int wave = tid >> 6;

    // bijective XCD swizzle (gridDim.x = 4000, %8==0)
    int nwg = gridDim.x;
    int bid = blockIdx.x;
    int qq  = nwg >> 3;
    int swz = (bid & 7)*qq + (bid >> 3);
    int tower = (swz >= 2000) ? 1 : 0;
    int id = swz - tower*2000;

    const u16* Ain    = tower ? Ain1  : Ain0;
    const u16* W      = tower ? W1    : W0;
    const float* bias = tower ? bias1 : bias0;
    u16* Oh           = tower ? Oh1   : Oh0;

    int nblk = id & 1;               // NB=2
    int mblk = id >> 1;
    int nimg = mblk / 125;
    int rem  = mblk - nimg*125;
    int ht   = rem / 5;
    int wt5  = rem - ht*5;
    int h0 = ht*4, w0 = wt5*32;
    int co0 = nblk*128;

    // staging source offsets. slot s: p=s>>3 row, ch=s&7 16B chunk; chs = ch ^ (p&7).
    int aoff[4], boff[4];
    #pragma unroll
    for (int it=0; it<4; ++it){
        int s = it*256 + tid;
        int p = s >> 3, ch = s & 7;
        int chs = ch ^ (p & 7);
        int i = p >> 5, j = p & 31;
        aoff[it] = ((nimg*HP + h0 + i)*WP + (w0 + j))*256 + chs*8;
        boff[it] = (co0 + p)*256 + chs*8;
    }
    const int ldst = wave*512;   // wave-uniform LDS dest (u16), + it*2048

    // fragment-read lane constants (step-invariant)
    const int l31 = lane & 31;
    const int q5  = lane >> 5;
    const int wm = wave >> 1, wn = wave & 1;
    int aRd[2][4], bRd[2][4];
    #pragma unroll
    for (int mt=0; mt<2; ++mt){
        int row = wm*64 + mt*32 + l31;
        #pragma unroll
        for (int ks=0; ks<4; ++ks){
            int c = ks*2 + q5;
            aRd[mt][ks] = row*64 + (c ^ (row & 7))*8;
        }
    }
    #pragma unroll
    for (int nt=0; nt<2; ++nt){
        int co = wn*64 + nt*32 + l31;
        #pragma unroll
        for (int ks=0; ks<4; ++ks){
            int c = ks*2 + q5;
            bRd[nt][ks] = 8192 + co*64 + (c ^ (co & 7))*8;
        }
    }

    f32x16 acc[2][2];
    #pragma unroll
    for (int mt=0;mt<2;mt++)
        #pragma unroll
        for (int nt=0;nt<2;nt++)
            acc[mt][nt] = (f32x16)0.0f;

    auto stage = [&](int t, int b){
        int tap = t >> 2, kb = t & 3;
        int kh = tap/3, kw = tap - kh*3;
        int adel = (kh*WP + kw)*256 + kb*64;
        int bdel = tap*65536 + kb*64;        // tap*256co*256ci
        u16* L = lds + b*16384;
        #pragma unroll
        for (int it=0; it<4; ++it)
            g2l16(Ain + aoff[it] + adel, L +        it*2048 + ldst);
        #pragma unroll
        for (int it=0; it<4; ++it)
            g2l16(W + bdel + boff[it], L + 8192 + it*2048 + ldst);
    };

    // prologue: prime both buffers; wait buf0 (buf1's 8 loads stay in flight)
    stage(0, 0);
    stage(1, 1);
    asm volatile("s_waitcnt vmcnt(8)" ::: "memory");
    __builtin_amdgcn_s_barrier();

    for (int t=0; t<36; ++t){
        int b = t & 1;
        const u16* L = lds + b*16384;
        f16x8 af[2][4], bf[2][4];
        #pragma unroll
        for (int mt=0;mt<2;mt++)
            #pragma unroll
            for (int ks=0;ks<4;ks++)
                af[mt][ks] = *(const f16x8*)(L + aRd[mt][ks]);
        #pragma unroll
        for (int nt=0;nt<2;nt++)
            #pragma unroll
            for (int ks=0;ks<4;ks++)
                bf[nt][ks] = *(const f16x8*)(L + bRd[nt][ks]);
        asm volatile("s_waitcnt lgkmcnt(0)" ::: "memory");   // my reads of buf[b] done
        __builtin_amdgcn_s_barrier();                        // ALL waves done reading buf[b]
        __builtin_amdgcn_sched_barrier(0);
        if (t < 34) stage(t+2, b);                           // WAR-safe overwrite of buf[b]
        __builtin_amdgcn_s_setprio(1);
        #pragma unroll
        for (int nt=0;nt<2;nt++)
            #pragma unroll
            for (int mt=0;mt<2;mt++)
                #pragma unroll
                for (int ks=0;ks<4;ks++)
                    acc[mt][nt] = __builtin_amdgcn_mfma_f32_32x32x16_f16(af[mt][ks], bf[nt][ks], acc[mt][nt], 0,0,0);
        __builtin_amdgcn_s_setprio(0);
        __builtin_amdgcn_sched_barrier(0);
        if (t < 34) { asm volatile("s_waitcnt vmcnt(8)" ::: "memory"); }  // stage(t+1) landed
        else        { asm volatile("s_waitcnt vmcnt(0)" ::: "memory"); }
        __builtin_amdgcn_s_barrier();                        // buf[b^1] staged for all waves
    }

    float bcol[2];
    #pragma unroll
    for (int nt=0;nt<2;nt++) bcol[nt] = bias[co0 + wn*64 + nt*32 + l31];

    // acc -> fp16 via LDS repack -> 16B contiguous stores
    // C/D: col = l31, row = (reg&3) + 8*(reg>>2) + 4*q5
    #pragma unroll
    for (int mt=0;mt<2;mt++)
        #pragma unroll
        for (int nt=0;nt<2;nt++)
            #pragma unroll
            for (int reg=0;reg<16;reg++){
                float v = fmaxf(acc[mt][nt][reg] + bcol[nt], 0.f);
                int p = wm*64 + mt*32 + (reg & 3) + 8*(reg >> 2) + 4*q5;
                int c = wn*64 + nt*32 + l31;
                lds[p*128 + c] = f2h(v);
            }
    __syncthreads();
    #pragma unroll
    for (int it=0; it<8; ++it){
        int s = it*256 + tid;
        int p = s >> 4, chh = s & 15;
        int i = p >> 5, j = p & 31;
        if (w0 + j < WW){
            size_t dst = ((size_t)((nimg*HP + h0 + i + 1)*WP + (w0 + j + 1)))*256 + co0 + chh*8;
            *(u16x8*)(Oh + dst) = *(const u16x8*)(lds + p*128 + chh*8);
        }
    }
}

// ---------------- fused dual-head conv (r14's proven MODE-3 kernel, 16x16x32) ----------------
// blocks [0,nPerTower) = pred+ctn on box-y4 (O1/O2); [nPerTower,2n) = score on cls-x4 (O3).
__global__ __launch_bounds__(256, 2) void conv_head(
    const u16* __restrict__ Ain0, const u16* __restrict__ Ain1,
    const u16* __restrict__ W0,  const u16* __restrict__ W1,
    const float* __restrict__ bias0, const float* __restrict__ bias1,
    float* __restrict__ O1, float* __restrict__ O2, float* __restrict__ O3,
    int nPerTower, int COUTP)
{
    constexpr int MR = 2;
    constexpr int NR = 5;

    __shared__ u16 lds[32768];
    const int tid  = threadIdx.x;
    const int lane = tid & 63;
    const int wave = tid >> 6;

    int nwg = gridDim.x;
    int bid = blockIdx.x;
    int qq  = nwg >> 3;
    int swz = (bid & 7)*qq + (bid >> 3);
    int tower = (swz >= nPerTower) ? 1 : 0;
    int id = swz - tower*nPerTower;

    const u16* Ain    = tower ? Ain1  : Ain0;
    const u16* W      = tower ? W1    : W0;
    const float* bias = tower ? bias1 : bias0;

    int mblk = id;
    int nimg = mblk / 125;
    int rem  = mblk - nimg*125;
    int ht   = rem / 5;
    int wt5  = rem - ht*5;
    int h0 = ht*4, w0 = wt5*32;

    int aoff[4], boff[4];
    #pragma unroll
    for (int it=0; it<4; ++it){
        int s = it*256 + tid;
        int p = s >> 3, ch = s & 7;
        int chs = ch ^ (p & 7);
        int i = p >> 5, j = p & 31;
        aoff[it] = ((nimg*HP + h0 + i)*WP + (w0 + j))*256 + chs*8;
        boff[it] = p*256 + chs*8;
    }
    const int ldst = wave*512;

    const int r  = lane & 15;
    const int q4 = lane >> 4;
    const int c0k = ((q4    ) ^ (r & 7)) * 8;
    const int c1k = ((q4 + 4) ^ (r & 7)) * 8;
    const int wm = wave;
    const int aBase = (wm*(MR*16) + r)*64;
    const int bBase = 8192 + r*64;

    f32x4 acc[MR][NR];
    #pragma unroll
    for (int m=0;m<MR;m++)
        #pragma unroll
        for (int n=0;n<NR;n++)
            acc[m][n] = (f32x4)0.0f;

    auto stage = [&](int t, int b){
        int tap = t >> 2, kb = t & 3;
        int kh = tap/3, kw = tap - kh*3;
        int adel = (kh*WP + kw)*256 + kb*64;
        int bdel = tap*COUTP*256 + kb*64;
        u16* L = lds + b*16384;
        #pragma unroll
        for (int it=0; it<4; ++it)
            g2l16(Ain + aoff[it] + adel, L +        it*2048 + ldst);
        #pragma unroll
        for (int it=0; it<4; ++it)
            g2l16(W + bdel + boff[it], L + 8192 + it*2048 + ldst);
    };

    stage(0, 0);
    stage(1, 1);
    asm volatile("s_waitcnt vmcnt(8)" ::: "memory");
    __builtin_amdgcn_s_barrier();

    for (int t=0; t<36; ++t){
        int b = t & 1;
        const u16* L = lds + b*16384;
        f16x8 a0[MR], a1[MR], b0[NR], b1[NR];
        #pragma unroll
        for (int m=0;m<MR;m++){
            a0[m] = *(const f16x8*)(L + aBase + m*1024 + c0k);
            a1[m] = *(const f16x8*)(L + aBase + m*1024 + c1k);
        }
        #pragma unroll
        for (int n=0;n<NR;n++){
            b0[n] = *(const f16x8*)(L + bBase + n*1024 + c0k);
            b1[n] = *(const f16x8*)(L + bBase + n*1024 + c1k);
        }
        asm volatile("s_waitcnt lgkmcnt(0)" ::: "memory");
        __builtin_amdgcn_s_barrier();
        __builtin_amdgcn_sched_barrier(0);
        if (t < 34) stage(t+2, b);
        __builtin_amdgcn_s_setprio(1);
        #pragma unroll
        for (int n=0;n<NR;n++)
            #pragma unroll
            for (int m=0;m<MR;m++){
                acc[m][n] = __builtin_amdgcn_mfma_f32_16x16x32_f16(a0[m], b0[n], acc[m][n], 0,0,0);
                acc[m][n] = __builtin_amdgcn_mfma_f32_16x16x32_f16(a1[m], b1[n], acc[m][n], 0,0,0);
            }
        __builtin_amdgcn_s_setprio(0);
        __builtin_amdgcn_sched_barrier(0);
        if (t < 34) { asm volatile("s_waitcnt vmcnt(8)" ::: "memory"); }
        else        { asm volatile("s_waitcnt vmcnt(0)" ::: "memory"); }
        __builtin_amdgcn_s_barrier();
    }

    float bcol[NR];
    #pragma unroll
    for (int n=0;n<NR;n++) bcol[n] = bias[n*16 + r];

    #pragma unroll
    for (int m=0;m<MR;m++)
        #pragma unroll
        for (int n=0;n<NR;n++)
            #pragma unroll
            for (int jj=0;jj<4;jj++){
                float v = acc[m][n][jj] + bcol[n];
                int p = wm*32 + m*16 + q4*4 + jj;
                int c = n*16 + r;
                int i = p >> 5, j = p & 31;
                if (w0 + j < WW){
                    int pix = nimg*(HH*WW) + (h0+i)*WW + (w0+j);
                    if (tower == 0){
                        if (c < 64)       O1[(size_t)pix*64 + c] = v;
                        else if (c == 64) O2[pix] = v;
                    } else {
                        if (c == 0) O3[pix] = v;
                    }
                }
            }
}

// ---------------- fused stat (softmax / erf-pmf / top4) + conf 1x1 convs + sigmoid*sigmoid ----------------
__global__ __launch_bounds__(256) void fuse_stat(
    const float* __restrict__ bbox, const float* __restrict__ cls_score,
    const float* __restrict__ w1, const float* __restrict__ b1,
    const float* __restrict__ w2, const float* __restrict__ b2,
    float* __restrict__ pred_cls)
{
    __shared__ float sstat[48][256];
    int tid = threadIdx.x;
    int pix = blockIdx.x*256 + tid;
    if (pix >= NPIX) return;
    const f32x4* row4 = (const f32x4*)(bbox + (size_t)pix*64);
    for (int g=0; g<4; ++g){
        f32x4 v0 = row4[g*4+0], v1 = row4[g*4+1], v2 = row4[g*4+2], v3 = row4[g*4+3];
        float lg[8], ls[8];
        #pragma unroll
        for (int k=0;k<4;k++){ lg[k]=v0[k]; lg[4+k]=v1[k]; ls[k]=v2[k]; ls[4+k]=v3[k]; }
        float m = lg[0];
        #pragma unroll
        for (int k=1;k<8;k++) m = fmaxf(m, lg[k]);
        float e[8], s = 0.f;
        #pragma unroll
        for (int k=0;k<8;k++){ e[k] = expf(lg[k]-m); s += e[k]; }
        float isum = 1.0f/s;
        float prob[8];
        #pragma unroll
        for (int k=0;k<8;k++) prob[k] = e[k]*isum;
        float pmf[8];
        #pragma unroll
        for (int k=0;k<8;k++) pmf[k] = 0.f;
        #pragma unroll
        for (int i=0;i<8;i++){
            float invi = 1.0f/(expf(ls[i]) * 1.41421356237309515f);
            float pi = prob[i];
            #pragma unroll
            for (int j=0;j<8;j++){
                float d = (float)(j - i);
                pmf[j] = fmaf(0.5f*(erff((d+1.0f)*invi) - erff((d-1.0f)*invi)), pi, pmf[j]);
            }
        }
        int used = 0;
        #pragma unroll
        for (int t=0;t<4;t++){
            float bv = -3.0e38f; int bi = 0;
            #pragma unroll
            for (int j=0;j<8;j++){
                bool ok = (((used>>j)&1)==0) && (pmf[j] > bv);
                bv = ok ? pmf[j] : bv;
                bi = ok ? j : bi;
            }
            used |= (1<<bi);
            float sl=0.f, sp=0.f;
            #pragma unroll
            for (int j=0;j<8;j++){ if (j==bi){ sl=ls[j]; sp=prob[j]; } }
            sstat[g*4+t][tid]    = sl;
            sstat[16+g*4+t][tid] = sp;
            sstat[32+g*4+t][tid] = bv;
        }
    }
    float q = b2[0];
    for (int u=0; u<64; ++u){
        float h = b1[u];
        #pragma unroll
        for (int c=0;c<48;c++) h = fmaf(sstat[c][tid], w1[u*48+c], h);
        q = fmaf(fmaxf(h,0.f), w2[u], q);
    }
    float quality = 1.0f/(1.0f+expf(-q));
    float cs = cls_score[pix];
    pred_cls[pix] = quality/(1.0f+expf(-cs));
}

// ---------------- launch ----------------
extern "C" void kernel_launch(void* const* d_in, const int* in_sizes, int n_in,
                              void* d_out, int out_size, void* d_ws, size_t ws_size,
                              hipStream_t stream) {
    (void)in_sizes; (void)n_in; (void)out_size;
    const float* feature = (const float*)d_in[0];
    const float* cls_w   = (const float*)d_in[1];
    const float* cls_b   = (const float*)d_in[2];
    const float* box_w   = (const float*)d_in[3];
    const float* box_b   = (const float*)d_in[4];
    const float* score_w = (const float*)d_in[5];
    const float* score_b = (const float*)d_in[6];
    const float* pred_w  = (const float*)d_in[7];
    const float* pred_b  = (const float*)d_in[8];
    const float* ctn_w   = (const float*)d_in[9];
    const float* ctn_b   = (const float*)d_in[10];
    const float* conf_w1 = (const float*)d_in[11];
    const float* conf_b1 = (const float*)d_in[12];
    const float* conf_w2 = (const float*)d_in[13];
    const float* conf_b2 = (const float*)d_in[14];

    float* out      = (float*)d_out;
    float* pred_cls = out;
    float* pred_reg = out + NPIX;
    float* pred_ctn = out + NPIX + (size_t)NPIX*64;

    char* ws = (char*)d_ws;
    size_t off = 0;
    auto alloc = [&](size_t b){ size_t rr = off; off += (b + 255) & ~(size_t)255; return rr; };
    u16* aA = (u16*)(ws + alloc(ACT_BYTES + 65536));   // cls ping
    u16* aB = (u16*)(ws + alloc(ACT_BYTES + 65536));   // cls pong
    u16* aC = (u16*)(ws + alloc(ACT_BYTES + 65536));   // box ping
    u16* aD = (u16*)(ws + alloc(ACT_BYTES + 65536));   // box pong
    const size_t TWR = (size_t)4*9*256*256;   // tower wt elements
    const size_t HDW = (size_t)9*128*256;     // head wt elements (128-padded)
    u16* wCls = (u16*)(ws + alloc(TWR*2));
    u16* wBox = (u16*)(ws + alloc(TWR*2));
    u16* wSc  = (u16*)(ws + alloc(HDW*2));
    u16* wPc  = (u16*)(ws + alloc(HDW*2));
    float* bPc = (float*)(ws + alloc(128*4));
    float* bSc = (float*)(ws + alloc(128*4));
    float* clsScore = (float*)(ws + alloc((size_t)NPIX*4));
    if (ws_size < off) return;   // insufficient workspace: bail (bench will flag)

    dim3 B(256);
    // prep
    zero_borders<<<508, B, 0, stream>>>(aA, aB, aC, aD);
    wt_tower<<<18432, B, 0, stream>>>(cls_w, box_w, wCls, wBox);
    wt_score<<<1152, B, 0, stream>>>(score_w, wSc);
    wt_predctn<<<1152, B, 0, stream>>>(pred_w, ctn_w, wPc);
    prep_bias<<<1, 128, 0, stream>>>(pred_b, ctn_b, score_b, bPc, bSc);

    const size_t LW = (size_t)9*256*256;      // per-layer tower wt elements
    // single feature transform feeds both (independent) tower chains
    feat2act<<<9600, B, 0, stream>>>(feature, aA, aC);
    // fused dual-tower layers (32x32 MFMA): cls A<->B, box C<->D
    conv_tower32<<<4000, B, 0, stream>>>(aA, aC, wCls+0*LW, wBox+0*LW, cls_b+0*256, box_b+0*256, aB, aD);
    conv_tower32<<<4000, B, 0, stream>>>(aB, aD, wCls+1*LW, wBox+1*LW, cls_b+1*256, box_b+1*256, aA, aC);
    conv_tower32<<<4000, B, 0, stream>>>(aA, aC, wCls+2*LW, wBox+2*LW, cls_b+2*256, box_b+2*256, aB, aD);
    conv_tower32<<<4000, B, 0, stream>>>(aB, aD, wCls+3*LW, wBox+3*LW, cls_b+3*256, box_b+3*256, aA, aC);
    // fused dual-head: blocks 0..999 pred+ctn on box-y4 (aC); 1000..1999 score on cls-x4 (aA)
    conv_head<<<2000, B, 0, stream>>>(aC, aA, wPc, wSc, bPc, bSc, pred_reg, pred_ctn, clsScore, 1000, 128);
    // fused stat + conf + final cls
    fuse_stat<<<475, B, 0, stream>>>(pred_reg, clsScore, conf_w1, conf_b1, conf_w2, conf_b2, pred_cls);
}

// Round 16
// 1361.600 us; speedup vs baseline: 1.1336x; 1.1336x over previous
//
#include <hip/hip_runtime.h>

typedef unsigned short u16;
typedef _Float16 f16;
typedef __attribute__((ext_vector_type(4))) float f32x4;
typedef __attribute__((ext_vector_type(8))) _Float16 f16x8;
typedef __attribute__((ext_vector_type(8))) unsigned short u16x8;

#define NIMG 8
#define HH 100
#define WW 152
#define HP 102
#define WP 154
#define NPIX (NIMG*HH*WW)                       // 121600
#define ACT_ELEMS ((size_t)NIMG*HP*WP*256)      // 32,169,984
#define ACT_BYTES (ACT_ELEMS*2)

__device__ __forceinline__ u16 f2h(float x){
    f16 h = (f16)x;                       // v_cvt_f16_f32, RNE
    return __builtin_bit_cast(u16, h);
}

__device__ __forceinline__ void g2l16(const u16* g, u16* l){
    __builtin_amdgcn_global_load_lds((const __attribute__((address_space(1))) unsigned int*)g,
                                     (__attribute__((address_space(3))) unsigned int*)l, 16, 0, 0);
}

// ---------------- border zeroing (pads of all four ping-pong activation buffers) ----------------
__global__ void zero_borders(u16* A, u16* B, u16* C, u16* D){
    int id = blockIdx.x*256 + threadIdx.x;            // 8*508*32 = 130048 exact
    int ch = id & 31; int t = id >> 5;
    int pb = t % 508; int nimg = t / 508;
    int hp, wp;
    if (pb < 154)      { hp = 0;            wp = pb; }
    else if (pb < 308) { hp = 101;          wp = pb - 154; }
    else if (pb < 408) { hp = pb - 308 + 1; wp = 0; }
    else               { hp = pb - 408 + 1; wp = 153; }
    size_t off = ((size_t)((nimg*HP + hp)*WP + wp))*256 + ch*8;
    u16x8 z = {};
    *(u16x8*)(A+off) = z; *(u16x8*)(B+off) = z;
    *(u16x8*)(C+off) = z; *(u16x8*)(D+off) = z;
}

// ---------------- NCHW fp32 feature -> padded NHWC fp16 (both tower inputs) ----------------
__global__ void feat2act(const float* __restrict__ F, u16* __restrict__ D1, u16* __restrict__ D2){
    __shared__ float t[64][65];
    int bid = blockIdx.x;
    int wb = bid % 3; bid /= 3;
    int cb = bid & 3; bid >>= 2;
    int h = bid % 100; int nimg = bid / 100;
    int c0 = cb*64, w0 = wb*64;
    int tid = threadIdx.x;
    int cl = tid >> 6;
    int wl = tid & 63;
    #pragma unroll
    for (int rr=0; rr<16; ++rr){
        int c = rr*4 + cl;
        int w = w0 + wl;
        float v = 0.f;
        if (w < WW) v = F[ ((size_t)((nimg*256 + c0 + c)*HH + h))*WW + w ];
        t[c][wl] = v;
    }
    __syncthreads();
    int wl2 = tid >> 6;
    int cl2 = tid & 63;
    #pragma unroll
    for (int rr=0; rr<16; ++rr){
        int w = rr*4 + wl2;
        if (w0 + w < WW){
            u16 h16 = f2h(t[cl2][w]);
            size_t dst = ((size_t)((nimg*HP + h + 1)*WP + (w0 + w + 1)))*256 + c0 + cl2;
            D1[dst] = h16;
            D2[dst] = h16;
        }
    }
}

// ---------------- weight transforms: OIHW fp32 -> [tap][co][ci] fp16 ----------------
__global__ void wt_tower(const float* __restrict__ srcC, const float* __restrict__ srcB,
                         u16* __restrict__ dC, u16* __restrict__ dB){
    int gidx = blockIdx.x*256 + threadIdx.x;       // 2 * 4*9*256*256
    const int HALF = 4*9*256*256;
    const float* src = (gidx < HALF) ? srcC : srcB;
    u16* d           = (gidx < HALF) ? dC : dB;
    int idx = (gidx < HALF) ? gidx : gidx - HALF;
    int ci = idx & 255; int t = idx >> 8;
    int co = t & 255; t >>= 8;
    int tap = t % 9; int l = t / 9;
    d[idx] = f2h(src[ ((size_t)((l*256+co)*256+ci))*9 + tap ]);
}
__global__ void wt_predctn(const float* __restrict__ pw, const float* __restrict__ cw,
                           u16* __restrict__ d){
    int idx = blockIdx.x*256 + threadIdx.x;        // 9*128*256 exact (1152 blocks)
    int ci = idx & 255; int co = (idx>>8) & 127; int tap = idx >> 15;
    float v = 0.f;
    if (co < 64)       v = pw[ ((size_t)(co*256+ci))*9 + tap ];
    else if (co == 64) v = cw[ (size_t)ci*9 + tap ];
    d[idx] = f2h(v);
}
__global__ void wt_score(const float* __restrict__ sw, u16* __restrict__ d){
    int idx = blockIdx.x*256 + threadIdx.x;        // 9*128*256 exact (1152 blocks)
    int ci = idx & 255; int co = (idx>>8) & 127; int tap = idx >> 15;
    d[idx] = f2h((co == 0) ? sw[ (size_t)ci*9 + tap ] : 0.f);
}
__global__ void prep_bias(const float* pb, const float* cb, const float* sb, float* bpc, float* bsc){
    int i = threadIdx.x;      // 128
    bpc[i] = (i < 64) ? pb[i] : ((i == 64) ? cb[0] : 0.f);
    bsc[i] = (i == 0) ? sb[0] : 0.f;
}

// ---------------- conv3x3 implicit GEMM, fp16 single-pass, 128x128 tile, BK=64 ----------------
// r14's proven core (938 TF dual-tower): 2 LDS buffers, per step:
// ds_read frags -> lgkmcnt(0) -> barrier -> stage(t+2, just-read buf) -> MFMA -> vmcnt(8) -> barrier.
// MODE 0: fused dual-tower (tile id selects cls/box pointers), waves 2Mx2N, MR4xNR4.
// MODE 3: fused dual-head — blocks [0,nPerTower) = pred+ctn on box-y4 (O1/O2),
//         blocks [nPerTower,2n) = score on cls-x4 (O3). Waves 4M, MR2xNR5, COUTP=128.
template<int MODE>
__global__ __launch_bounds__(256, 2) void conv3x3_k(
    const u16* __restrict__ Ain0, const u16* __restrict__ Ain1,
    const u16* __restrict__ W0,  const u16* __restrict__ W1,
    const float* __restrict__ bias0, const float* __restrict__ bias1,
    u16* __restrict__ Oh0, u16* __restrict__ Oh1,
    float* __restrict__ O1, float* __restrict__ O2, float* __restrict__ O3,
    int nPerTower, int NB, int COUTP)
{
    constexpr int MR = (MODE==0) ? 4 : 2;
    constexpr int NR = (MODE==0) ? 4 : 5;

    __shared__ u16 lds[32768];   // 64 KiB (2 buffers; buf stride 16384: A@0, B@8192)
    const int tid  = threadIdx.x;
    const int lane = tid & 63;
    const int wave = tid >> 6;

    // bijective XCD swizzle (gridDim.x % 8 == 0)
    int nwg = gridDim.x;
    int bid = blockIdx.x;
    int qq  = nwg >> 3;
    int swz = (bid & 7)*qq + (bid >> 3);
    int tower = (swz >= nPerTower) ? 1 : 0;
    int id = swz - tower*nPerTower;

    const u16* Ain    = tower ? Ain1  : Ain0;
    const u16* W      = tower ? W1    : W0;
    const float* bias = tower ? bias1 : bias0;
    u16* Oh           = tower ? Oh1   : Oh0;

    int nblk = id % NB;
    int mblk = id / NB;
    int nimg = mblk / 125;
    int rem  = mblk - nimg*125;
    int ht   = rem / 5;
    int wt5  = rem - ht*5;
    int h0 = ht*4, w0 = wt5*32;
    int co0 = nblk*128;

    // staging source offsets. slot s: p=s>>3 row, ch=s&7 16B chunk; chs = ch ^ (p&7).
    int aoff[4], boff[4];
    #pragma unroll
    for (int it=0; it<4; ++it){
        int s = it*256 + tid;
        int p = s >> 3, ch = s & 7;
        int chs = ch ^ (p & 7);
        int i = p >> 5, j = p & 31;
        aoff[it] = ((nimg*HP + h0 + i)*WP + (w0 + j))*256 + chs*8;
        boff[it] = (co0 + p)*256 + chs*8;
    }
    const int ldst = wave*512;   // wave-uniform LDS dest (u16), + it*2048

    // fragment-read lane constants
    const int r  = lane & 15;
    const int q4 = lane >> 4;
    const int c0k = ((q4    ) ^ (r & 7)) * 8;   // swizzled k-chunk, kk=0
    const int c1k = ((q4 + 4) ^ (r & 7)) * 8;   // kk=1
    int wm, wn;
    if (MODE == 0){ wm = wave >> 1; wn = wave & 1; } else { wm = wave; wn = 0; }
    const int aBase = (wm*(MR*16) + r)*64;
    const int bBase = 8192 + (wn*64 + r)*64;

    f32x4 acc[MR][NR];
    #pragma unroll
    for (int m=0;m<MR;m++)
        #pragma unroll
        for (int n=0;n<NR;n++)
            acc[m][n] = (f32x4)0.0f;

    auto stage = [&](int t, int b){
        int tap = t >> 2, kb = t & 3;
        int kh = tap/3, kw = tap - kh*3;
        int adel = (kh*WP + kw)*256 + kb*64;
        int bdel = tap*COUTP*256 + kb*64;
        u16* L = lds + b*16384;
        #pragma unroll
        for (int it=0; it<4; ++it)
            g2l16(Ain + aoff[it] + adel, L +        it*2048 + ldst);
        #pragma unroll
        for (int it=0; it<4; ++it)
            g2l16(W + bdel + boff[it], L + 8192 + it*2048 + ldst);
    };

    // prologue: prime both buffers; wait buf0 (buf1's 8 loads stay in flight)
    stage(0, 0);
    stage(1, 1);
    asm volatile("s_waitcnt vmcnt(8)" ::: "memory");
    __builtin_amdgcn_s_barrier();

    for (int t=0; t<36; ++t){
        int b = t & 1;
        const u16* L = lds + b*16384;
        f16x8 a0[MR], a1[MR], b0[NR], b1[NR];
        #pragma unroll
        for (int m=0;m<MR;m++){
            a0[m] = *(const f16x8*)(L + aBase + m*1024 + c0k);
            a1[m] = *(const f16x8*)(L + aBase + m*1024 + c1k);
        }
        #pragma unroll
        for (int n=0;n<NR;n++){
            b0[n] = *(const f16x8*)(L + bBase + n*1024 + c0k);
            b1[n] = *(const f16x8*)(L + bBase + n*1024 + c1k);
        }
        asm volatile("s_waitcnt lgkmcnt(0)" ::: "memory");   // my reads of buf[b] done
        __builtin_amdgcn_s_barrier();                        // ALL waves done reading buf[b]
        __builtin_amdgcn_sched_barrier(0);
        if (t < 34) stage(t+2, b);                           // WAR-safe overwrite of buf[b]
        __builtin_amdgcn_s_setprio(1);
        #pragma unroll
        for (int n=0;n<NR;n++){
            #pragma unroll
            for (int m=0;m<MR;m++){
                acc[m][n] = __builtin_amdgcn_mfma_f32_16x16x32_f16(a0[m], b0[n], acc[m][n], 0,0,0);
                acc[m][n] = __builtin_amdgcn_mfma_f32_16x16x32_f16(a1[m], b1[n], acc[m][n], 0,0,0);
            }
        }
        __builtin_amdgcn_s_setprio(0);
        __builtin_amdgcn_sched_barrier(0);
        if (t < 34) { asm volatile("s_waitcnt vmcnt(8)" ::: "memory"); }  // stage(t+1) landed
        else        { asm volatile("s_waitcnt vmcnt(0)" ::: "memory"); }
        __builtin_amdgcn_s_barrier();                        // buf[b^1] staged for all waves
    }

    float bcol[NR];
    #pragma unroll
    for (int n=0;n<NR;n++) bcol[n] = bias[co0 + wn*64 + n*16 + r];

    if (MODE == 0){
        // acc -> fp16 via LDS repack -> 16B contiguous stores
        #pragma unroll
        for (int m=0;m<MR;m++)
            #pragma unroll
            for (int n=0;n<NR;n++)
                #pragma unroll
                for (int jj=0;jj<4;jj++){
                    float v = fmaxf(acc[m][n][jj] + bcol[n], 0.f);
                    int p = wm*64 + m*16 + q4*4 + jj;
                    int c = wn*64 + n*16 + r;
                    lds[p*128 + c] = f2h(v);
                }
        __syncthreads();
        #pragma unroll
        for (int it=0; it<8; ++it){
            int s = it*256 + tid;
            int p = s >> 4, chh = s & 15;
            int i = p >> 5, j = p & 31;
            if (w0 + j < WW){
                size_t dst = ((size_t)((nimg*HP + h0 + i + 1)*WP + (w0 + j + 1)))*256 + co0 + chh*8;
                *(u16x8*)(Oh + dst) = *(const u16x8*)(lds + p*128 + chh*8);
            }
        }
    } else {
        // MODE 3 dual-head epilogue: tower 0 = pred+ctn -> O1/O2; tower 1 = score -> O3
        #pragma unroll
        for (int m=0;m<MR;m++)
            #pragma unroll
            for (int n=0;n<NR;n++)
                #pragma unroll
                for (int jj=0;jj<4;jj++){
                    float v = acc[m][n][jj] + bcol[n];
                    int p = wm*32 + m*16 + q4*4 + jj;
                    int c = n*16 + r;
                    int i = p >> 5, j = p & 31;
                    if (w0 + j < WW){
                        int pix = nimg*(HH*WW) + (h0+i)*WW + (w0+j);
                        if (tower == 0){
                            if (c < 64)       O1[(size_t)pix*64 + c] = v;
                            else if (c == 64) O2[pix] = v;
                        } else {
                            if (c == 0) O3[pix] = v;
                        }
                    }
                }
    }
}

// ---------------- fused stat (softmax / erf-pmf / top4) + conf 1x1 convs + sigmoid*sigmoid ----------------
__global__ __launch_bounds__(256) void fuse_stat(
    const float* __restrict__ bbox, const float* __restrict__ cls_score,
    const float* __restrict__ w1, const float* __restrict__ b1,
    const float* __restrict__ w2, const float* __restrict__ b2,
    float* __restrict__ pred_cls)
{
    __shared__ float sstat[48][256];
    int tid = threadIdx.x;
    int pix = blockIdx.x*256 + tid;
    if (pix >= NPIX) return;
    const f32x4* row4 = (const f32x4*)(bbox + (size_t)pix*64);
    for (int g=0; g<4; ++g){
        f32x4 v0 = row4[g*4+0], v1 = row4[g*4+1], v2 = row4[g*4+2], v3 = row4[g*4+3];
        float lg[8], ls[8];
        #pragma unroll
        for (int k=0;k<4;k++){ lg[k]=v0[k]; lg[4+k]=v1[k]; ls[k]=v2[k]; ls[4+k]=v3[k]; }
        float m = lg[0];
        #pragma unroll
        for (int k=1;k<8;k++) m = fmaxf(m, lg[k]);
        float e[8], s = 0.f;
        #pragma unroll
        for (int k=0;k<8;k++){ e[k] = expf(lg[k]-m); s += e[k]; }
        float isum = 1.0f/s;
        float prob[8];
        #pragma unroll
        for (int k=0;k<8;k++) prob[k] = e[k]*isum;
        float pmf[8];
        #pragma unroll
        for (int k=0;k<8;k++) pmf[k] = 0.f;
        #pragma unroll
        for (int i=0;i<8;i++){
            float invi = 1.0f/(expf(ls[i]) * 1.41421356237309515f);
            float pi = prob[i];
            #pragma unroll
            for (int j=0;j<8;j++){
                float d = (float)(j - i);
                pmf[j] = fmaf(0.5f*(erff((d+1.0f)*invi) - erff((d-1.0f)*invi)), pi, pmf[j]);
            }
        }
        int used = 0;
        #pragma unroll
        for (int t=0;t<4;t++){
            float bv = -3.0e38f; int bi = 0;
            #pragma unroll
            for (int j=0;j<8;j++){
                bool ok = (((used>>j)&1)==0) && (pmf[j] > bv);
                bv = ok ? pmf[j] : bv;
                bi = ok ? j : bi;
            }
            used |= (1<<bi);
            float sl=0.f, sp=0.f;
            #pragma unroll
            for (int j=0;j<8;j++){ if (j==bi){ sl=ls[j]; sp=prob[j]; } }
            sstat[g*4+t][tid]    = sl;
            sstat[16+g*4+t][tid] = sp;
            sstat[32+g*4+t][tid] = bv;
        }
    }
    float q = b2[0];
    for (int u=0; u<64; ++u){
        float h = b1[u];
        #pragma unroll
        for (int c=0;c<48;c++) h = fmaf(sstat[c][tid], w1[u*48+c], h);
        q = fmaf(fmaxf(h,0.f), w2[u], q);
    }
    float quality = 1.0f/(1.0f+expf(-q));
    float cs = cls_score[pix];
    pred_cls[pix] = quality/(1.0f+expf(-cs));
}

// ---------------- launch ----------------
extern "C" void kernel_launch(void* const* d_in, const int* in_sizes, int n_in,
                              void* d_out, int out_size, void* d_ws, size_t ws_size,
                              hipStream_t stream) {
    (void)in_sizes; (void)n_in; (void)out_size;
    const float* feature = (const float*)d_in[0];
    const float* cls_w   = (const float*)d_in[1];
    const float* cls_b   = (const float*)d_in[2];
    const float* box_w   = (const float*)d_in[3];
    const float* box_b   = (const float*)d_in[4];
    const float* score_w = (const float*)d_in[5];
    const float* score_b = (const float*)d_in[6];
    const float* pred_w  = (const float*)d_in[7];
    const float* pred_b  = (const float*)d_in[8];
    const float* ctn_w   = (const float*)d_in[9];
    const float* ctn_b   = (const float*)d_in[10];
    const float* conf_w1 = (const float*)d_in[11];
    const float* conf_b1 = (const float*)d_in[12];
    const float* conf_w2 = (const float*)d_in[13];
    const float* conf_b2 = (const float*)d_in[14];

    float* out      = (float*)d_out;
    float* pred_cls = out;
    float* pred_reg = out + NPIX;
    float* pred_ctn = out + NPIX + (size_t)NPIX*64;

    char* ws = (char*)d_ws;
    size_t off = 0;
    auto alloc = [&](size_t b){ size_t rr = off; off += (b + 255) & ~(size_t)255; return rr; };
    u16* aA = (u16*)(ws + alloc(ACT_BYTES + 65536));   // cls ping
    u16* aB = (u16*)(ws + alloc(ACT_BYTES + 65536));   // cls pong
    u16* aC = (u16*)(ws + alloc(ACT_BYTES + 65536));   // box ping
    u16* aD = (u16*)(ws + alloc(ACT_BYTES + 65536));   // box pong
    const size_t TWR = (size_t)4*9*256*256;   // tower wt elements
    const size_t HDW = (size_t)9*128*256;     // head wt elements (128-padded)
    u16* wCls = (u16*)(ws + alloc(TWR*2));
    u16* wBox = (u16*)(ws + alloc(TWR*2));
    u16* wSc  = (u16*)(ws + alloc(HDW*2));
    u16* wPc  = (u16*)(ws + alloc(HDW*2));
    float* bPc = (float*)(ws + alloc(128*4));
    float* bSc = (float*)(ws + alloc(128*4));
    float* clsScore = (float*)(ws + alloc((size_t)NPIX*4));
    if (ws_size < off) return;   // insufficient workspace: bail (bench will flag)

    dim3 B(256);
    // prep
    zero_borders<<<508, B, 0, stream>>>(aA, aB, aC, aD);
    wt_tower<<<18432, B, 0, stream>>>(cls_w, box_w, wCls, wBox);
    wt_score<<<1152, B, 0, stream>>>(score_w, wSc);
    wt_predctn<<<1152, B, 0, stream>>>(pred_w, ctn_w, wPc);
    prep_bias<<<1, 128, 0, stream>>>(pred_b, ctn_b, score_b, bPc, bSc);

    const size_t LW = (size_t)9*256*256;      // per-layer tower wt elements
    // single feature transform feeds both (independent) tower chains
    feat2act<<<9600, B, 0, stream>>>(feature, aA, aC);
    // fused dual-tower layers: cls A<->B, box C<->D  (4000 blocks: first 2000 cls, rest box)
    conv3x3_k<0><<<4000, B, 0, stream>>>(aA, aC, wCls+0*LW, wBox+0*LW, cls_b+0*256, box_b+0*256, aB, aD, nullptr, nullptr, nullptr, 2000, 2, 256);
    conv3x3_k<0><<<4000, B, 0, stream>>>(aB, aD, wCls+1*LW, wBox+1*LW, cls_b+1*256, box_b+1*256, aA, aC, nullptr, nullptr, nullptr, 2000, 2, 256);
    conv3x3_k<0><<<4000, B, 0, stream>>>(aA, aC, wCls+2*LW, wBox+2*LW, cls_b+2*256, box_b+2*256, aB, aD, nullptr, nullptr, nullptr, 2000, 2, 256);
    conv3x3_k<0><<<4000, B, 0, stream>>>(aB, aD, wCls+3*LW, wBox+3*LW, cls_b+3*256, box_b+3*256, aA, aC, nullptr, nullptr, nullptr, 2000, 2, 256);
    // fused dual-head: blocks 0..999 pred+ctn on box-y4 (aC) -> pred_reg/pred_ctn;
    //                  blocks 1000..1999 score on cls-x4 (aA) -> clsScore
    conv3x3_k<3><<<2000, B, 0, stream>>>(aC, aA, wPc, wSc, bPc, bSc, nullptr, nullptr, pred_reg, pred_ctn, clsScore, 1000, 1, 128);
    // fused stat + conf + final cls
    fuse_stat<<<475, B, 0, stream>>>(pred_reg, clsScore, conf_w1, conf_b1, conf_w2, conf_b2, pred_cls);
}